// Round 9
// baseline (573.011 us; speedup 1.0000x reference)
//
#include <hip/hip_runtime.h>
#include <hip/hip_fp16.h>
#include <hip/hip_cooperative_groups.h>
#include <math.h>

namespace cg = cooperative_groups;

// Problem constants: B=8, Tt=16, C=1, H=W=512, 4 in-channels, 10 T-planes.
#define Bd 8
#define Td 16
#define Hd 512
#define Wd 512
#define HWc (Hd * Wd)          // 262144
#define NPIX (Bd * HWc)        // 2,097,152

// ---------------- conv tiling: 128x8 tile, 2 px/thread, 512 threads ----------
#define CTW 128
#define CTH 8
#define CRW 130
#define CRH 10
#define CPITCH 132
#define CTHR 512

// ---------------- fused-step tiling ------------------------------------------
#define TS   64
#define H6   6
#define RS   76                // TS + 2*H6
#define LP   77                // LDS row pitch
#define NTHR 768
#define RPG  8                 // owned rows per thread
#define NG   10                // row groups

// ---------------------------------------------------------------------------
// Kernel 1: tiled conv  T = conv2d(x[:, -4:, 0], W_unet, SAME) + b_unet,
// fused with xt0 = stencil(x[:,15,0], T_fp32) -> out[:, 0].
// T stored as half2 pairs: plane q holds (T[2q], T[2q+1]); layout (B,5,H,W).
// ---------------------------------------------------------------------------
__global__ __launch_bounds__(CTHR)
void conv_step0_kernel(const float* __restrict__ x,
                       const float* __restrict__ Wu,
                       const float* __restrict__ bu,
                       __half2* __restrict__ T,
                       float* __restrict__ out) {
    __shared__ __align__(16) float sX[4][CRH][CPITCH];

    int bx  = blockIdx.x;           // 2048 = 8 b * 64 row-bands * 4 col-bands
    int b   = bx >> 8;
    int rem = bx & 255;
    int by  = rem >> 2;
    int bc  = rem & 3;
    int i0  = by * CTH;
    int j0  = bc * CTW;

    const float* xb = x + ((size_t)b * Td + 12) * HWc;
    int tid = threadIdx.x;

    for (int idx = tid; idx < 4 * CRH * CRW; idx += CTHR) {
        int ch = idx / (CRH * CRW);
        int r2 = idx - ch * (CRH * CRW);
        int r  = r2 / CRW;
        int c  = r2 - r * CRW;
        int gi = i0 + r - 1, gj = j0 + c - 1;
        float v = 0.0f;
        if ((unsigned)gi < (unsigned)Hd && (unsigned)gj < (unsigned)Wd)
            v = xb[(size_t)ch * HWc + gi * Wd + gj];
        sX[ch][r][c] = v;
    }
    __syncthreads();

    int tx = tid & 63;              // pixel pair: cols 2tx, 2tx+1
    int ty = tid >> 6;              // tile row 0..7

    float t0[10], t1[10];
    #pragma unroll
    for (int o = 0; o < 10; ++o) { float bv = bu[o]; t0[o] = bv; t1[o] = bv; }

    #pragma unroll
    for (int ch = 0; ch < 4; ++ch)
        #pragma unroll
        for (int kh = 0; kh < 3; ++kh) {
            const float* rp = &sX[ch][ty + kh][2 * tx];
            float2 a  = *(const float2*)rp;
            float2 b2 = *(const float2*)(rp + 2);
            float w0 = a.x, w1 = a.y, w2 = b2.x, w3 = b2.y;
            #pragma unroll
            for (int o = 0; o < 10; ++o) {
                float wt0 = Wu[((o * 4 + ch) * 3 + kh) * 3 + 0];
                float wt1 = Wu[((o * 4 + ch) * 3 + kh) * 3 + 1];
                float wt2 = Wu[((o * 4 + ch) * 3 + kh) * 3 + 2];
                t0[o] += w0 * wt0 + w1 * wt1 + w2 * wt2;
                t1[o] += w1 * wt0 + w2 * wt1 + w3 * wt2;
            }
        }

    int gi = i0 + ty;
    int gjv = j0 + 2 * tx;
    size_t pix = (size_t)gi * Wd + gjv;
    __half2* Tb = T + (size_t)b * 5 * HWc;
    #pragma unroll
    for (int q = 0; q < 5; ++q) {
        __half2 h0 = __floats2half2_rn(t0[2 * q], t0[2 * q + 1]);
        __half2 h1 = __floats2half2_rn(t1[2 * q], t1[2 * q + 1]);
        uint2 pk;
        pk.x = *(unsigned*)&h0;
        pk.y = *(unsigned*)&h1;
        *(uint2*)(Tb + (size_t)q * HWc + pix) = pk;
    }

    // step0 on channel 3 (slice 15), fp32 coefficients.
    float o0 = t0[9], o1 = t1[9];
    #pragma unroll
    for (int di = 0; di < 3; ++di) {
        const float* rp = &sX[3][ty + di][2 * tx];
        float2 a  = *(const float2*)rp;
        float2 b2 = *(const float2*)(rp + 2);
        float w0 = a.x, w1 = a.y, w2 = b2.x, w3 = b2.y;
        #pragma unroll
        for (int dj = 0; dj < 3; ++dj) {
            float xa = (dj == 0) ? w0 : ((dj == 1) ? w1 : w2);
            float xc = (dj == 0) ? w1 : ((dj == 1) ? w2 : w3);
            o0 += xa * t0[dj * 3 + di];
            o1 += xc * t1[dj * 3 + di];
        }
    }
    float2 ov; ov.x = o0; ov.y = o1;
    *(float2*)(out + (size_t)b * Td * HWc + pix) = ov;
}

// ---------------------------------------------------------------------------
// Kernel 2 (cooperative, persistent): ALL 15 scan iterations in one launch.
// 256 blocks; block i owns tiles i and i+256 (processed sequentially per
// iteration), keeping BOTH tiles' 40 fp16 T coefs in VGPRs for the whole
// kernel (80 VGPR). Per tile per iteration: stage 76x76 region from
// out[:,t-1], 6 LDS ping-pong stencil steps (identical to round 7), write
// core to out[:,t]; grid.sync() between iterations.
// Occupancy: 768 thr = 12 waves; launch_bounds(768,4) caps VGPR at 128 ->
// 16 waves/CU -> 1 block/CU -> 256 co-resident blocks. LDS 46.8 KB < 64 KB.
// ---------------------------------------------------------------------------
__global__ __launch_bounds__(NTHR, 4)
void scan_persistent2_kernel(const __half2* __restrict__ T,
                             float* __restrict__ out) {
    cg::grid_group grid = cg::this_grid();

    __shared__ float sA[RS * LP];
    __shared__ float sB[RS * LP];

    int tid = threadIdx.x;

    // Zero sB's ring ONCE (ring cells are never written by the step loop;
    // interior is fully rewritten each step before being read).
    for (int idx = tid; idx < 4 * RS; idx += NTHR) {
        int side = idx / RS, k = idx - side * RS;
        int r, c;
        if (side == 0)      { r = 0;      c = k; }
        else if (side == 1) { r = RS - 1; c = k; }
        else if (side == 2) { r = k;      c = 0; }
        else                { r = k;      c = RS - 1; }
        sB[r * LP + c] = 0.0f;
    }

    // Thread decomposition (identical to round 7).
    int g  = tid / RS;              // row group 0..9 valid
    int c  = tid - g * RS;          // column 0..75
    int rs = 1 + g * RPG;           // first owned row
    bool colint = (c >= 1) && (c <= RS - 2);
    bool active = (g < NG) && colint;

    // Geometry + T coefficients for both owned tiles (loaded ONCE).
    int  ri_[2], rj_[2], b_[2];
    bool colin_[2];
    __half2 treg[2][RPG][5];
    #pragma unroll
    for (int tt = 0; tt < 2; ++tt) {
        int tile = blockIdx.x + tt * 256;    // 0..511
        int b   = tile >> 6;
        int trr = (tile >> 3) & 7;
        int tcc = tile & 7;
        b_[tt]  = b;
        ri_[tt] = trr * TS - H6;
        rj_[tt] = tcc * TS - H6;
        int gj  = rj_[tt] + c;
        colin_[tt] = (unsigned)gj < (unsigned)Wd;
        const __half2* Tb = T + (size_t)b * 5 * HWc;
        #pragma unroll
        for (int jj = 0; jj < RPG; ++jj) {
            int r  = rs + jj;
            int gi = ri_[tt] + r;
            bool ok = active && (r <= RS - 2) &&
                      ((unsigned)gi < (unsigned)Hd) && colin_[tt];
            #pragma unroll
            for (int q = 0; q < 5; ++q)
                treg[tt][jj][q] = ok ? Tb[(size_t)q * HWc + gi * Wd + gj]
                                     : __floats2half2_rn(0.0f, 0.0f);
        }
    }

    for (int t = 1; t < Td; ++t) {
        #pragma unroll
        for (int tt = 0; tt < 2; ++tt) {
            int ri = ri_[tt], rj = rj_[tt];
            bool colin = colin_[tt];

            // Stage sA from out[:, t-1] (zeros outside image).
            const float* xb = out + ((size_t)b_[tt] * Td + (t - 1)) * HWc;
            for (int idx = tid; idx < RS * RS; idx += NTHR) {
                int r = idx / RS, cc = idx - r * RS;
                int gi2 = ri + r, gj2 = rj + cc;
                float v = 0.0f;
                if ((unsigned)gi2 < (unsigned)Hd && (unsigned)gj2 < (unsigned)Wd)
                    v = xb[gi2 * Wd + gj2];
                sA[r * LP + cc] = v;
            }
            __syncthreads();

            float* cur = sA;
            float* nxt = sB;

            #pragma unroll
            for (int s = 1; s <= 6; ++s) {
                if (active) {
                    float w00 = cur[(rs - 1) * LP + c - 1];
                    float w01 = cur[(rs - 1) * LP + c];
                    float w02 = cur[(rs - 1) * LP + c + 1];
                    float w10 = cur[rs * LP + c - 1];
                    float w11 = cur[rs * LP + c];
                    float w12 = cur[rs * LP + c + 1];
                    #pragma unroll
                    for (int jj = 0; jj < RPG; ++jj) {
                        int r  = rs + jj;
                        int r2 = (r + 1 <= RS - 1) ? (r + 1) : (RS - 1);  // clamp
                        float w20 = cur[r2 * LP + c - 1];
                        float w21 = cur[r2 * LP + c];
                        float w22 = cur[r2 * LP + c + 1];

                        float2 p0 = __half22float2(treg[tt][jj][0]);  // T0,T1
                        float2 p1 = __half22float2(treg[tt][jj][1]);  // T2,T3
                        float2 p2 = __half22float2(treg[tt][jj][2]);  // T4,T5
                        float2 p3 = __half22float2(treg[tt][jj][3]);  // T6,T7
                        float2 p4 = __half22float2(treg[tt][jj][4]);  // T8,T9

                        // k = dj*3+di multiplies x[r+di-1][c+dj-1]
                        float a = p4.y
                                + w00 * p0.x + w10 * p0.y + w20 * p1.x
                                + w01 * p1.y + w11 * p2.x + w21 * p2.y
                                + w02 * p3.x + w12 * p3.y + w22 * p4.x;
                        if ((s & 1) == 0) a = 1.0f / (1.0f + __expf(-a));

                        int gi2 = ri + r;
                        bool rowok = (r <= RS - 2);
                        bool inimg = ((unsigned)gi2 < (unsigned)Hd) && colin;
                        if (rowok) nxt[r * LP + c] = inimg ? a : 0.0f;

                        w00 = w10; w01 = w11; w02 = w12;
                        w10 = w20; w11 = w21; w12 = w22;
                    }
                }
                __syncthreads();
                float* tmp = cur; cur = nxt; nxt = tmp;
            }

            // After 6 swaps result is in sA. Write the 64x64 core to out[:, t].
            float* ob = out + ((size_t)b_[tt] * Td + t) * HWc;
            for (int idx = tid; idx < TS * TS; idx += NTHR) {
                int rr = idx >> 6, cc = idx & 63;
                ob[(ri + H6 + rr) * Wd + (rj + H6 + cc)] =
                    sA[(H6 + rr) * LP + (H6 + cc)];
            }
            __syncthreads();   // write-loop reads sA; next stage overwrites it
        }
        grid.sync();           // out[:, t] visible device-wide
    }
}

// ---------------------------------------------------------------------------
// Fallback kernel (round-7 exact): one scan iteration per launch.
// ---------------------------------------------------------------------------
__global__ __launch_bounds__(NTHR, 6)
void fused6_vstrip_kernel(const float* __restrict__ xin,
                          const __half2* __restrict__ T,
                          float* __restrict__ xout) {
    __shared__ float sA[RS * LP];
    __shared__ float sB[RS * LP];

    int tile = blockIdx.x;
    int b   = tile >> 6;
    int trr = (tile >> 3) & 7;
    int tcc = tile & 7;
    int ri = trr * TS - H6;
    int rj = tcc * TS - H6;

    const float* xb = xin + (size_t)b * Td * HWc;
    const __half2* Tb = T + (size_t)b * 5 * HWc;
    int tid = threadIdx.x;

    for (int idx = tid; idx < RS * RS; idx += NTHR) {
        int r = idx / RS, c = idx - r * RS;
        int gi = ri + r, gj = rj + c;
        float v = 0.0f;
        if ((unsigned)gi < (unsigned)Hd && (unsigned)gj < (unsigned)Wd)
            v = xb[gi * Wd + gj];
        sA[r * LP + c] = v;
    }
    for (int idx = tid; idx < 4 * RS; idx += NTHR) {
        int side = idx / RS, k = idx - side * RS;
        int r, c;
        if (side == 0)      { r = 0;      c = k; }
        else if (side == 1) { r = RS - 1; c = k; }
        else if (side == 2) { r = k;      c = 0; }
        else                { r = k;      c = RS - 1; }
        sB[r * LP + c] = 0.0f;
    }

    int g  = tid / RS;
    int c  = tid - g * RS;
    int rs = 1 + g * RPG;
    bool colint = (c >= 1) && (c <= RS - 2);
    bool active = (g < NG) && colint;
    int  gj     = rj + c;
    bool colin  = (unsigned)gj < (unsigned)Wd;

    __half2 treg[RPG][5];
    #pragma unroll
    for (int jj = 0; jj < RPG; ++jj) {
        int r  = rs + jj;
        int gi = ri + r;
        bool ok = active && (r <= RS - 2) && ((unsigned)gi < (unsigned)Hd) && colin;
        #pragma unroll
        for (int q = 0; q < 5; ++q)
            treg[jj][q] = ok ? Tb[(size_t)q * HWc + gi * Wd + gj]
                             : __floats2half2_rn(0.0f, 0.0f);
    }
    __syncthreads();

    float* cur = sA;
    float* nxt = sB;

    #pragma unroll
    for (int s = 1; s <= 6; ++s) {
        if (active) {
            float w00 = cur[(rs - 1) * LP + c - 1];
            float w01 = cur[(rs - 1) * LP + c];
            float w02 = cur[(rs - 1) * LP + c + 1];
            float w10 = cur[rs * LP + c - 1];
            float w11 = cur[rs * LP + c];
            float w12 = cur[rs * LP + c + 1];
            #pragma unroll
            for (int jj = 0; jj < RPG; ++jj) {
                int r  = rs + jj;
                int r2 = (r + 1 <= RS - 1) ? (r + 1) : (RS - 1);
                float w20 = cur[r2 * LP + c - 1];
                float w21 = cur[r2 * LP + c];
                float w22 = cur[r2 * LP + c + 1];

                float2 p0 = __half22float2(treg[jj][0]);
                float2 p1 = __half22float2(treg[jj][1]);
                float2 p2 = __half22float2(treg[jj][2]);
                float2 p3 = __half22float2(treg[jj][3]);
                float2 p4 = __half22float2(treg[jj][4]);

                float a = p4.y
                        + w00 * p0.x + w10 * p0.y + w20 * p1.x
                        + w01 * p1.y + w11 * p2.x + w21 * p2.y
                        + w02 * p3.x + w12 * p3.y + w22 * p4.x;
                if ((s & 1) == 0) a = 1.0f / (1.0f + __expf(-a));

                int gi = ri + r;
                bool rowok = (r <= RS - 2);
                bool inimg = ((unsigned)gi < (unsigned)Hd) && colin;
                if (rowok) nxt[r * LP + c] = inimg ? a : 0.0f;

                w00 = w10; w01 = w11; w02 = w12;
                w10 = w20; w11 = w21; w12 = w22;
            }
        }
        __syncthreads();
        float* tmp = cur; cur = nxt; nxt = tmp;
    }

    float* ob = xout + (size_t)b * Td * HWc;
    for (int idx = tid; idx < TS * TS; idx += NTHR) {
        int rr = idx >> 6, cc = idx & 63;
        ob[(ri + H6 + rr) * Wd + (rj + H6 + cc)] = cur[(H6 + rr) * LP + (H6 + cc)];
    }
}

// ---------------------------------------------------------------------------
// Workspace: T only (B*5*H*W half2 = 40 MB).
// ---------------------------------------------------------------------------
extern "C" void kernel_launch(void* const* d_in, const int* in_sizes, int n_in,
                              void* d_out, int out_size, void* d_ws, size_t ws_size,
                              hipStream_t stream) {
    const float* x  = (const float*)d_in[0];
    const float* Wu = (const float*)d_in[1];
    const float* bu = (const float*)d_in[2];
    float* out = (float*)d_out;
    __half2* T = (__half2*)d_ws;

    conv_step0_kernel<<<2048, CTHR, 0, stream>>>(x, Wu, bu, T, out);

    // Cooperative-launch capability gate (host-side query, capture-safe,
    // deterministic on a given device).
    int nb = 0;
    hipError_t qe = hipOccupancyMaxActiveBlocksPerMultiprocessor(
        &nb, scan_persistent2_kernel, NTHR, 0);
    bool coop_ok = (qe == hipSuccess) && (nb >= 1);

    if (coop_ok) {
        const __half2* Tc = T;
        float* oc = out;
        void* args[] = { (void*)&Tc, (void*)&oc };
        hipError_t le = hipLaunchCooperativeKernel(
            (const void*)scan_persistent2_kernel,
            dim3(256), dim3(NTHR), args, 0, stream);
        if (le == hipSuccess) return;
    }

    // Fallback: proven round-7 path (one launch per scan iteration).
    for (int t = 1; t < Td; ++t)
        fused6_vstrip_kernel<<<512, NTHR, 0, stream>>>(out + (size_t)(t - 1) * HWc, T,
                                                       out + (size_t)t * HWc);
}